// Round 15
// baseline (91.233 us; speedup 1.0000x reference)
//
#include <hip/hip_runtime.h>
#include <hip/hip_bf16.h>

#define B_ 256
#define S_ 70
#define D_ 128
#define NSAMP 12
#define NNODE 40000
#define HGLOB (B_ * S_ * D_)
#define IBLK 14             // i-rows per local M-tile (5 tiles cover 70)
#define NPOS 12             // s-positions per global block (6 blocks cover 70, clamped)
#define NR2 (NPOS * NSAMP)  // 144 neighbor rows = exactly 9 M-tiles
#define NROLE 9             // 3 local + 6 global blocks per b

typedef float  f32x4 __attribute__((ext_vector_type(4)));
typedef short  s16x8 __attribute__((ext_vector_type(8)));

__device__ __forceinline__ unsigned short f2bf(float x) {
    union { float f; unsigned u; } v; v.f = x;
    return (unsigned short)((v.u + 0x7FFF + ((v.u >> 16) & 1)) >> 16);  // RNE
}
__device__ __forceinline__ float bf2f(unsigned short u) {
    union { unsigned u; float f; } v; v.u = ((unsigned)u) << 16;
    return v.f;
}

// ---- prelude: sess (blocks 0..255) + weight pack (256..351) + embT cast (352..1601) ----
__global__ __launch_bounds__(512) void prelude_kernel(const int* __restrict__ item,
                                                      const int* __restrict__ mask,
                                                      const float* __restrict__ emb,
                                                      const float* __restrict__ gw1,
                                                      const float* __restrict__ gw3,
                                                      float* __restrict__ sess,
                                                      unsigned short* __restrict__ gw1T,
                                                      unsigned short* __restrict__ gw3T,
                                                      unsigned short* __restrict__ embT) {
    if (blockIdx.x < B_) {
        __shared__ float pacc[4][D_];
        __shared__ float pm[4];
        int b = blockIdx.x;
        int d = threadIdx.x & 127, q = threadIdx.x >> 7;
        float acc = 0.f, msum = 0.f;
        for (int s = q; s < S_; s += 4) {
            int node = item[b * S_ + s];
            float m = (float)mask[b * S_ + s];
            acc += m * emb[(long)node * D_ + d];
            msum += m;
        }
        pacc[q][d] = acc;
        if (d == 0) pm[q] = msum;
        __syncthreads();
        if (q == 0) {
            float a = pacc[0][d] + pacc[1][d] + pacc[2][d] + pacc[3][d];
            float m = pm[0] + pm[1] + pm[2] + pm[3];
            sess[b * D_ + d] = a / m;
        }
    } else if (blockIdx.x < B_ + 96) {
        int idx = (blockIdx.x - B_) * 512 + threadIdx.x;   // 0..49151
        if (idx < 128 * 128) {                             // gw1T[c][r]
            int c = idx >> 7, r = idx & 127;
            gw1T[idx] = f2bf(gw1[r * 128 + c]);
        } else if (idx < 128 * 128 + 128 * 256) {          // gw3T[c][r]
            int j = idx - 128 * 128;
            int c = j >> 8, r = j & 255;
            gw3T[j] = f2bf(gw3[r * 128 + c]);
        }
    } else {
        long idx = (long)(blockIdx.x - (B_ + 96)) * 512 + threadIdx.x;
        if (idx < (long)NNODE * D_ / 8) {
            const float4* src = (const float4*)(emb + idx * 8);
            float4 e0 = src[0], e1 = src[1];
            s16x8 p;
            p[0] = (short)f2bf(e0.x); p[1] = (short)f2bf(e0.y);
            p[2] = (short)f2bf(e0.z); p[3] = (short)f2bf(e0.w);
            p[4] = (short)f2bf(e1.x); p[5] = (short)f2bf(e1.y);
            p[6] = (short)f2bf(e1.z); p[7] = (short)f2bf(e1.w);
            *(s16x8*)(embT + idx * 8) = p;
        }
    }
}

// ---------------- fused local+global, role by blockIdx ----------------
struct LocalSM {
    unsigned short hl[72 * 128];   // 18432 B, chunk-swizzled ^(row&7)
    float          El[16 * 84];    //  5376 B
    unsigned short al[16 * 104];   //  3328 B
    int            ids[72];        //   288 B
};                                 // 27424 B
struct GlobalSM {
    unsigned short nv[NR2 * 128];  // 36864 B, chunk-swizzled (144 rows, no pad)
    unsigned short cat[16 * 256];  //  8192 B
    float          spart[NR2][4];  //  2304 B
    float          nw[NR2];        //   576 B
    float          score[NR2];     //   576 B
    float          wsm[NR2];       //   576 B
};                                 // 49088 B

union FusedSM { LocalSM loc; GlobalSM glob; };

__global__ __launch_bounds__(256) void fused_kernel(
        const int* __restrict__ inputs, const int* __restrict__ adj,
        const int* __restrict__ adj_all, const float* __restrict__ num_w,
        const unsigned short* __restrict__ embT, const float* __restrict__ sess,
        const float* __restrict__ a0p, const float* __restrict__ a1p,
        const float* __restrict__ a2p, const float* __restrict__ a3p,
        const unsigned short* __restrict__ gw1T, const float* __restrict__ gw1,
        const float* __restrict__ gw2,
        const unsigned short* __restrict__ gw3T, const float* __restrict__ gbias,
        float* __restrict__ out) {
    __shared__ __align__(16) FusedSM smem;

    const int L = blockIdx.x;
    const int b = L / NROLE;
    const int r = L - b * NROLE;
    const int tid  = threadIdx.x;
    const int lane = tid & 63, wave = tid >> 6;
    const int l15  = lane & 15, l4 = lane >> 4;
    const s16x8 zero8 = {0, 0, 0, 0, 0, 0, 0, 0};

    if (r < 3) {
        // ========== LOCAL role: two 16-row M-tiles of h_local, H staged once ==========
        LocalSM* P = &smem.loc;

        // phase A: ids + zero pad rows 70,71 of hl
        if (tid < S_) P->ids[tid] = inputs[b * S_ + tid];
        if (tid < 32) ((s16x8*)P->hl)[70 * 16 + tid] = zero8;
        __syncthreads();

        // phase B: stage hl (bf16 table read, chunk-swizzled)
        #pragma unroll
        for (int it = 0; it < 5; ++it) {
            int idx = it * 256 + tid;
            if (idx < S_ * 16) {
                int s = idx >> 4, c8 = idx & 15;
                s16x8 p = *(const s16x8*)(embT + (long)P->ids[s] * D_ + c8 * 8);
                ((s16x8*)P->hl)[s * 16 + (c8 ^ (s & 7))] = p;
            }
        }
        __syncthreads();

        const int tEnd = (r * 2 + 2 > 5) ? 5 : r * 2 + 2;
        for (int t = r * 2; t < tEnd; ++t) {
            const int i0 = t * IBLK;

            // phase C: E tiles (4 relations via MFMA), select by adj
            s16x8 af_all[4][4];
            {
                const float* aptr[4] = {a0p, a1p, a2p, a3p};
                int hrow = i0 + l15;                    // <= 71 (pad rows zero)
                #pragma unroll
                for (int ks = 0; ks < 4; ++ks) {
                    s16x8 hf = ((s16x8*)P->hl)[hrow * 16 + ((ks * 4 + l4) ^ (hrow & 7))];
                    #pragma unroll
                    for (int rr = 0; rr < 4; ++rr) {
                        const float* ar = aptr[rr];
                        float4 alo = *(const float4*)(ar + ks * 32 + l4 * 8);
                        float4 ahi = *(const float4*)(ar + ks * 32 + l4 * 8 + 4);
                        s16x8 o;
                        o[0] = (short)f2bf(bf2f((unsigned short)hf[0]) * alo.x);
                        o[1] = (short)f2bf(bf2f((unsigned short)hf[1]) * alo.y);
                        o[2] = (short)f2bf(bf2f((unsigned short)hf[2]) * alo.z);
                        o[3] = (short)f2bf(bf2f((unsigned short)hf[3]) * alo.w);
                        o[4] = (short)f2bf(bf2f((unsigned short)hf[4]) * ahi.x);
                        o[5] = (short)f2bf(bf2f((unsigned short)hf[5]) * ahi.y);
                        o[6] = (short)f2bf(bf2f((unsigned short)hf[6]) * ahi.z);
                        o[7] = (short)f2bf(bf2f((unsigned short)hf[7]) * ahi.w);
                        af_all[rr][ks] = o;
                    }
                }
            }

            for (int n = wave; n < 5; n += 4) {
                s16x8 bfr[4];
                int jr = n * 16 + l15;
                int jrc = jr < 72 ? jr : 71;
                #pragma unroll
                for (int ks = 0; ks < 4; ++ks)
                    bfr[ks] = ((s16x8*)P->hl)[jrc * 16 + ((ks * 4 + l4) ^ (jrc & 7))];

                f32x4 ac0 = {0.f,0.f,0.f,0.f}, ac1 = {0.f,0.f,0.f,0.f};
                f32x4 ac2 = {0.f,0.f,0.f,0.f}, ac3 = {0.f,0.f,0.f,0.f};
                #pragma unroll
                for (int ks = 0; ks < 4; ++ks) {
                    ac0 = __builtin_amdgcn_mfma_f32_16x16x32_bf16(af_all[0][ks], bfr[ks], ac0, 0, 0, 0);
                    ac1 = __builtin_amdgcn_mfma_f32_16x16x32_bf16(af_all[1][ks], bfr[ks], ac1, 0, 0, 0);
                    ac2 = __builtin_amdgcn_mfma_f32_16x16x32_bf16(af_all[2][ks], bfr[ks], ac2, 0, 0, 0);
                    ac3 = __builtin_amdgcn_mfma_f32_16x16x32_bf16(af_all[3][ks], bfr[ks], ac3, 0, 0, 0);
                }

                #pragma unroll
                for (int reg = 0; reg < 4; ++reg) {
                    int il = l4 * 4 + reg;
                    int i  = i0 + il;
                    int j  = n * 16 + l15;
                    float v;
                    if (j < S_) {
                        int ic = i < S_ ? i : S_ - 1;
                        int a  = adj[((long)b * S_ + ic) * S_ + j];
                        float raw = (a == 1) ? ac0[reg] : (a == 2) ? ac1[reg]
                                  : (a == 3) ? ac2[reg] : (a == 4) ? ac3[reg] : 0.f;
                        v = (a >= 1 && a <= 4) ? (raw > 0.f ? raw : 0.2f * raw) : -9e15f;
                    } else {
                        v = -INFINITY;
                    }
                    P->El[il * 84 + j] = v;
                }
            }
            __syncthreads();

            // phase D: row softmax + pack alpha bf16 (zero for j >= 70)
            {
                int g = tid >> 4, li = tid & 15;
                float mx = -INFINITY;
                for (int j = li; j < S_; j += 16) mx = fmaxf(mx, P->El[g * 84 + j]);
                #pragma unroll
                for (int o = 1; o < 16; o <<= 1) mx = fmaxf(mx, __shfl_xor(mx, o));
                float sm = 0.f;
                for (int j = li; j < S_; j += 16) {
                    float ex = __expf(P->El[g * 84 + j] - mx);
                    P->El[g * 84 + j] = ex;
                    sm += ex;
                }
                #pragma unroll
                for (int o = 1; o < 16; o <<= 1) sm += __shfl_xor(sm, o);
                float inv = 1.f / sm;
                for (int j = li; j < 104; j += 16)
                    P->al[g * 104 + j] = (j < S_) ? f2bf(P->El[g * 84 + j] * inv) : (unsigned short)0;
            }
            __syncthreads();

            // phase E: h_local = alpha @ H; B-frags assembled from hl columns
            for (int n = wave; n < 8; n += 4) {
                f32x4 acc = {0.f, 0.f, 0.f, 0.f};
                int d = n * 16 + l15;
                int dchunk = d >> 3, de = d & 7;
                #pragma unroll
                for (int ks = 0; ks < 3; ++ks) {
                    s16x8 afp = *(const s16x8*)(P->al + l15 * 104 + ks * 32 + l4 * 8);
                    int jb = ks * 32 + l4 * 8;
                    s16x8 bfp;
                    #pragma unroll
                    for (int e = 0; e < 8; ++e) {
                        int j = jb + e;
                        bfp[e] = (j < 72)
                            ? (short)P->hl[j * 128 + ((dchunk ^ (j & 7)) << 3) + de]
                            : (short)0;
                    }
                    acc = __builtin_amdgcn_mfma_f32_16x16x32_bf16(afp, bfp, acc, 0, 0, 0);
                }
                #pragma unroll
                for (int reg = 0; reg < 4; ++reg) {
                    int il = l4 * 4 + reg;
                    if (il < IBLK)
                        out[((long)b * S_ + (i0 + il)) * D_ + d] = acc[reg];
                }
            }
            __syncthreads();   // protect El/al before next tile
        }
    } else {
        // ========== GLOBAL role: NPOS positions of h_global (clamped tail) ==========
        GlobalSM* P = &smem.glob;
        const int i0  = (r - 3) * NPOS;
        const int bs0 = b * S_ + i0;

        // phase A: neighbor ids handled inline; nw to LDS (positions >= 70 clamped)
        __shared__ int neigh_s[NR2];
        if (tid < NR2) {
            int p = tid / NSAMP;
            int k = tid - p * NSAMP;
            int pos = i0 + p; if (pos >= S_) pos = S_ - 1;
            int node = inputs[b * S_ + pos];
            neigh_s[tid] = adj_all[node * NSAMP + k];
            P->nw[tid]   = num_w[node * NSAMP + k];
        }
        __syncthreads();

        // phase B: stage nv from bf16 table, swizzled (9 exact iters)
        #pragma unroll
        for (int it = 0; it < 9; ++it) {
            int idx = it * 256 + tid;
            int row = idx >> 4, c8 = idx & 15;
            s16x8 p = *(const s16x8*)(embT + (long)neigh_s[row] * D_ + c8 * 8);
            ((s16x8*)P->nv)[row * 16 + (c8 ^ (row & 7))] = p;
        }
        __syncthreads();

        // phase C: B-fragments with sess folded
        s16x8 bfp[2][4];
        #pragma unroll
        for (int n = 0; n < 2; ++n) {
            int c = (wave * 2 + n) * 16 + l15;
            #pragma unroll
            for (int ks = 0; ks < 4; ++ks) {
                s16x8 g = *(const s16x8*)(gw1T + c * 128 + ks * 32 + l4 * 8);
                float4 slo = *(const float4*)(sess + b * D_ + ks * 32 + l4 * 8);
                float4 shi = *(const float4*)(sess + b * D_ + ks * 32 + l4 * 8 + 4);
                s16x8 o;
                o[0] = (short)f2bf(bf2f((unsigned short)g[0]) * slo.x);
                o[1] = (short)f2bf(bf2f((unsigned short)g[1]) * slo.y);
                o[2] = (short)f2bf(bf2f((unsigned short)g[2]) * slo.z);
                o[3] = (short)f2bf(bf2f((unsigned short)g[3]) * slo.w);
                o[4] = (short)f2bf(bf2f((unsigned short)g[4]) * shi.x);
                o[5] = (short)f2bf(bf2f((unsigned short)g[5]) * shi.y);
                o[6] = (short)f2bf(bf2f((unsigned short)g[6]) * shi.z);
                o[7] = (short)f2bf(bf2f((unsigned short)g[7]) * shi.w);
                bfp[n][ks] = o;
            }
        }
        float g128a = gw1[128 * 128 + wave * 32 + l15];
        float g128b = gw1[128 * 128 + wave * 32 + 16 + l15];
        float gw2a  = gw2[wave * 32 + l15];
        float gw2b  = gw2[wave * 32 + 16 + l15];

        // phase D: gw1 matmul over 9 M-tiles + score epilogue
        for (int m = 0; m < NR2 / 16; ++m) {
            int arow = m * 16 + l15;
            s16x8 af[4];
            #pragma unroll
            for (int ks = 0; ks < 4; ++ks)
                af[ks] = ((s16x8*)P->nv)[arow * 16 + ((ks * 4 + l4) ^ (arow & 7))];

            f32x4 acc0 = {0.f, 0.f, 0.f, 0.f}, acc1 = {0.f, 0.f, 0.f, 0.f};
            #pragma unroll
            for (int ks = 0; ks < 4; ++ks) {
                acc0 = __builtin_amdgcn_mfma_f32_16x16x32_bf16(af[ks], bfp[0][ks], acc0, 0, 0, 0);
                acc1 = __builtin_amdgcn_mfma_f32_16x16x32_bf16(af[ks], bfp[1][ks], acc1, 0, 0, 0);
            }

            float sp[4];
            #pragma unroll
            for (int reg = 0; reg < 4; ++reg) {
                int rr = m * 16 + l4 * 4 + reg;
                float nwv = P->nw[rr];
                float al0 = acc0[reg] + nwv * g128a;
                float al1 = acc1[reg] + nwv * g128b;
                al0 = al0 > 0.f ? al0 : 0.2f * al0;
                al1 = al1 > 0.f ? al1 : 0.2f * al1;
                sp[reg] = al0 * gw2a + al1 * gw2b;
            }
            #pragma unroll
            for (int off = 1; off < 16; off <<= 1) {
                #pragma unroll
                for (int reg = 0; reg < 4; ++reg) sp[reg] += __shfl_xor(sp[reg], off);
            }
            if (l15 == 0) {
                int rb = m * 16 + l4 * 4;
                #pragma unroll
                for (int reg = 0; reg < 4; ++reg) P->spart[rb + reg][wave] = sp[reg];
            }
        }
        __syncthreads();

        if (tid < NR2)
            P->score[tid] = P->spart[tid][0] + P->spart[tid][1] + P->spart[tid][2] + P->spart[tid][3];
        __syncthreads();

        if (tid < NPOS) {
            float mx = -1e30f;
            #pragma unroll
            for (int k = 0; k < NSAMP; ++k) mx = fmaxf(mx, P->score[tid * NSAMP + k]);
            float ex[NSAMP]; float ss = 0.f;
            #pragma unroll
            for (int k = 0; k < NSAMP; ++k) { ex[k] = __expf(P->score[tid * NSAMP + k] - mx); ss += ex[k]; }
            float inv = 1.f / ss;
            #pragma unroll
            for (int k = 0; k < NSAMP; ++k) P->wsm[tid * NSAMP + k] = ex[k] * inv;
        }
        __syncthreads();

        // phase E: nagg from LDS nv + cat staging (h from bf16 table, clamped pos)
        {
            int p  = tid >> 4;
            int c8 = tid & 15;
            if (p < NPOS) {
                float a0v[4] = {0.f,0.f,0.f,0.f}, a1v[4] = {0.f,0.f,0.f,0.f};
                #pragma unroll
                for (int k = 0; k < NSAMP; ++k) {
                    int row = p * NSAMP + k;
                    float w = P->wsm[row];
                    s16x8 nvv = ((s16x8*)P->nv)[row * 16 + (c8 ^ (row & 7))];
                    a0v[0] += w * bf2f((unsigned short)nvv[0]);
                    a0v[1] += w * bf2f((unsigned short)nvv[1]);
                    a0v[2] += w * bf2f((unsigned short)nvv[2]);
                    a0v[3] += w * bf2f((unsigned short)nvv[3]);
                    a1v[0] += w * bf2f((unsigned short)nvv[4]);
                    a1v[1] += w * bf2f((unsigned short)nvv[5]);
                    a1v[2] += w * bf2f((unsigned short)nvv[6]);
                    a1v[3] += w * bf2f((unsigned short)nvv[7]);
                }
                int pos = i0 + p; if (pos >= S_) pos = S_ - 1;
                int node = inputs[b * S_ + pos];
                s16x8 ph = *(const s16x8*)(embT + (long)node * D_ + c8 * 8);
                s16x8 pa;
                pa[0]=(short)f2bf(a0v[0]); pa[1]=(short)f2bf(a0v[1]); pa[2]=(short)f2bf(a0v[2]); pa[3]=(short)f2bf(a0v[3]);
                pa[4]=(short)f2bf(a1v[0]); pa[5]=(short)f2bf(a1v[1]); pa[6]=(short)f2bf(a1v[2]); pa[7]=(short)f2bf(a1v[3]);
                ((s16x8*)P->cat)[p * 32 + ( c8       ^ (p & 7))] = ph;
                ((s16x8*)P->cat)[p * 32 + ((16 + c8) ^ (p & 7))] = pa;
            } else {
                ((s16x8*)P->cat)[p * 32 + ( c8       ^ (p & 7))] = zero8;
                ((s16x8*)P->cat)[p * 32 + ((16 + c8) ^ (p & 7))] = zero8;
            }
        }
        __syncthreads();

        // phase F: gw3 matmul + bias + relu (store only real positions)
        {
            f32x4 acc0 = {0.f,0.f,0.f,0.f}, acc1 = {0.f,0.f,0.f,0.f};
            int arow = l15;
            int cc = wave * 32 + l15;
            #pragma unroll
            for (int ks = 0; ks < 8; ++ks) {
                s16x8 a  = ((s16x8*)P->cat)[arow * 32 + ((ks * 4 + l4) ^ (arow & 7))];
                s16x8 b0 = *(const s16x8*)(gw3T +  cc       * 256 + ks * 32 + l4 * 8);
                s16x8 b1 = *(const s16x8*)(gw3T + (cc + 16) * 256 + ks * 32 + l4 * 8);
                acc0 = __builtin_amdgcn_mfma_f32_16x16x32_bf16(a, b0, acc0, 0, 0, 0);
                acc1 = __builtin_amdgcn_mfma_f32_16x16x32_bf16(a, b1, acc1, 0, 0, 0);
            }
            float gb0 = gbias[wave * 32 + l15];
            float gb1 = gbias[wave * 32 + 16 + l15];
            #pragma unroll
            for (int reg = 0; reg < 4; ++reg) {
                int il = l4 * 4 + reg;
                if (il < NPOS && i0 + il < S_) {
                    long bs = bs0 + il;
                    float o0 = acc0[reg] + gb0;
                    float o1 = acc1[reg] + gb1;
                    out[(long)HGLOB + bs * D_ + wave * 32 + l15]      = o0 > 0.f ? o0 : 0.f;
                    out[(long)HGLOB + bs * D_ + wave * 32 + 16 + l15] = o1 > 0.f ? o1 : 0.f;
                }
            }
        }
    }
}

extern "C" void kernel_launch(void* const* d_in, const int* in_sizes, int n_in,
                              void* d_out, int out_size, void* d_ws, size_t ws_size,
                              hipStream_t stream) {
    const int*   inputs  = (const int*)  d_in[0];
    const int*   adj     = (const int*)  d_in[1];
    const int*   mask    = (const int*)  d_in[2];
    const int*   item    = (const int*)  d_in[3];
    const int*   adj_all = (const int*)  d_in[5];
    const float* num_w   = (const float*)d_in[6];
    const float* emb     = (const float*)d_in[7];
    const float* a0      = (const float*)d_in[8];
    const float* a1      = (const float*)d_in[9];
    const float* a2      = (const float*)d_in[10];
    const float* a3      = (const float*)d_in[11];
    const float* gw1     = (const float*)d_in[12];
    const float* gw2     = (const float*)d_in[13];
    const float* gw3     = (const float*)d_in[14];
    const float* gbias   = (const float*)d_in[15];
    float* out = (float*)d_out;

    float*          sess = (float*)d_ws;                              // 131072 B
    unsigned short* gw1T = (unsigned short*)((char*)d_ws + 131072);   // 32768 B
    unsigned short* gw3T = gw1T + 128 * 128;                          // 65536 B
    unsigned short* embT = gw3T + 128 * 256;                          // 10,240,000 B

    const int embt_blocks = (NNODE * D_ / 8 + 511) / 512;             // 1250
    prelude_kernel<<<B_ + 96 + embt_blocks, 512, 0, stream>>>(item, mask, emb, gw1, gw3,
                                                              sess, gw1T, gw3T, embT);
    fused_kernel<<<B_ * NROLE, 256, 0, stream>>>(inputs, adj, adj_all, num_w, embT, sess,
                                                 a0, a1, a2, a3,
                                                 gw1T, gw1, gw2, gw3T, gbias, out);
}

// Round 16
// 80.430 us; speedup vs baseline: 1.1343x; 1.1343x over previous
//
#include <hip/hip_runtime.h>
#include <hip/hip_bf16.h>

#define B_ 256
#define S_ 70
#define D_ 128
#define NSAMP 12
#define NNODE 40000
#define HGLOB (B_ * S_ * D_)
#define IBLK 14             // i-rows per local tile (5 tiles cover 70)
#define NPOS 10             // s-positions per global tile (7 tiles cover 70)
#define NR2 (NPOS * NSAMP)  // 120 neighbor rows
#define NRP 128             // padded to 8 M-tiles

typedef float  f32x4 __attribute__((ext_vector_type(4)));
typedef short  s16x8 __attribute__((ext_vector_type(8)));

__device__ __forceinline__ unsigned short f2bf(float x) {
    union { float f; unsigned u; } v; v.f = x;
    return (unsigned short)((v.u + 0x7FFF + ((v.u >> 16) & 1)) >> 16);  // RNE
}
__device__ __forceinline__ float bf2f(unsigned short u) {
    union { unsigned u; float f; } v; v.u = ((unsigned)u) << 16;
    return v.f;
}

// ---- prelude: sess (blocks 0..255) + weight pack (256..351) + embT cast (352..1601) ----
__global__ __launch_bounds__(512) void prelude_kernel(const int* __restrict__ item,
                                                      const int* __restrict__ mask,
                                                      const float* __restrict__ emb,
                                                      const float* __restrict__ gw1,
                                                      const float* __restrict__ gw3,
                                                      float* __restrict__ sess,
                                                      unsigned short* __restrict__ gw1T,
                                                      unsigned short* __restrict__ gw3T,
                                                      unsigned short* __restrict__ embT) {
    if (blockIdx.x < B_) {
        __shared__ float pacc[4][D_];
        __shared__ float pm[4];
        int b = blockIdx.x;
        int d = threadIdx.x & 127, q = threadIdx.x >> 7;
        float acc = 0.f, msum = 0.f;
        for (int s = q; s < S_; s += 4) {
            int node = item[b * S_ + s];
            float m = (float)mask[b * S_ + s];
            acc += m * emb[(long)node * D_ + d];
            msum += m;
        }
        pacc[q][d] = acc;
        if (d == 0) pm[q] = msum;
        __syncthreads();
        if (q == 0) {
            float a = pacc[0][d] + pacc[1][d] + pacc[2][d] + pacc[3][d];
            float m = pm[0] + pm[1] + pm[2] + pm[3];
            sess[b * D_ + d] = a / m;
        }
    } else if (blockIdx.x < B_ + 96) {
        int idx = (blockIdx.x - B_) * 512 + threadIdx.x;   // 0..49151
        if (idx < 128 * 128) {                             // gw1T[c][r]
            int c = idx >> 7, r = idx & 127;
            gw1T[idx] = f2bf(gw1[r * 128 + c]);
        } else if (idx < 128 * 128 + 128 * 256) {          // gw3T[c][r]
            int j = idx - 128 * 128;
            int c = j >> 8, r = j & 255;
            gw3T[j] = f2bf(gw3[r * 128 + c]);
        }
    } else {
        long idx = (long)(blockIdx.x - (B_ + 96)) * 512 + threadIdx.x;
        if (idx < (long)NNODE * D_ / 8) {
            const float4* src = (const float4*)(emb + idx * 8);
            float4 e0 = src[0], e1 = src[1];
            s16x8 p;
            p[0] = (short)f2bf(e0.x); p[1] = (short)f2bf(e0.y);
            p[2] = (short)f2bf(e0.z); p[3] = (short)f2bf(e0.w);
            p[4] = (short)f2bf(e1.x); p[5] = (short)f2bf(e1.y);
            p[6] = (short)f2bf(e1.z); p[7] = (short)f2bf(e1.w);
            *(s16x8*)(embT + idx * 8) = p;
        }
    }
}

// ---------------- fused local+global, role by blockIdx (R11 structure) ----------------
struct LocalSM {
    unsigned short hl[72 * 128];   // 18432 B, chunk-swizzled ^(row&7)
    float          El[16 * 84];    //  5376 B
    unsigned short al[16 * 104];   //  3328 B
    int            ids[72];        //   288 B
};                                 // 27424 B
struct GlobalSM {
    unsigned short nv[NRP * 128];  // 32768 B, chunk-swizzled
    unsigned short cat[16 * 256];  //  8192 B
    float          spart[NRP][4];  //  2048 B
    int            neigh[NR2];     //   480 B
    float          nw[NR2];        //   480 B
    float          score[NR2];     //   480 B
    float          wsm[NR2];       //   480 B
};                                 // 44928 B

union FusedSM { LocalSM loc; GlobalSM glob; };

__global__ __launch_bounds__(256) void fused_kernel(
        const int* __restrict__ inputs, const int* __restrict__ adj,
        const int* __restrict__ adj_all, const float* __restrict__ num_w,
        const unsigned short* __restrict__ embT, const float* __restrict__ sess,
        const float* __restrict__ a0p, const float* __restrict__ a1p,
        const float* __restrict__ a2p, const float* __restrict__ a3p,
        const unsigned short* __restrict__ gw1T, const float* __restrict__ gw1,
        const float* __restrict__ gw2,
        const unsigned short* __restrict__ gw3T, const float* __restrict__ gbias,
        float* __restrict__ out) {
    __shared__ __align__(16) FusedSM smem;

    const int L = blockIdx.x;
    const int b = L / 12;
    const int r = L - b * 12;
    const int tid  = threadIdx.x;
    const int lane = tid & 63, wave = tid >> 6;
    const int l15  = lane & 15, l4 = lane >> 4;
    const s16x8 zero8 = {0, 0, 0, 0, 0, 0, 0, 0};

    if (r < 5) {
        // ================= LOCAL role: one 16-row M-tile of h_local =================
        LocalSM* P = &smem.loc;
        const int i0 = r * IBLK;

        // phase A: ids + zero pad rows 70,71 of hl
        if (tid < S_) P->ids[tid] = inputs[b * S_ + tid];
        if (tid < 32) ((s16x8*)P->hl)[70 * 16 + tid] = zero8;
        __syncthreads();

        // phase B: stage hl (bf16 table read, chunk-swizzled; no cvt)
        #pragma unroll
        for (int it = 0; it < 5; ++it) {
            int idx = it * 256 + tid;
            if (idx < S_ * 16) {
                int s = idx >> 4, c8 = idx & 15;
                s16x8 p = *(const s16x8*)(embT + (long)P->ids[s] * D_ + c8 * 8);
                ((s16x8*)P->hl)[s * 16 + (c8 ^ (s & 7))] = p;
            }
        }
        __syncthreads();

        // phase C: E tiles (4 relations via MFMA), select by adj
        s16x8 af_all[4][4];
        {
            const float* aptr[4] = {a0p, a1p, a2p, a3p};
            int hrow = i0 + l15;
            #pragma unroll
            for (int ks = 0; ks < 4; ++ks) {
                s16x8 hf = ((s16x8*)P->hl)[hrow * 16 + ((ks * 4 + l4) ^ (hrow & 7))];
                #pragma unroll
                for (int rr = 0; rr < 4; ++rr) {
                    const float* ar = aptr[rr];
                    float4 alo = *(const float4*)(ar + ks * 32 + l4 * 8);
                    float4 ahi = *(const float4*)(ar + ks * 32 + l4 * 8 + 4);
                    s16x8 o;
                    o[0] = (short)f2bf(bf2f((unsigned short)hf[0]) * alo.x);
                    o[1] = (short)f2bf(bf2f((unsigned short)hf[1]) * alo.y);
                    o[2] = (short)f2bf(bf2f((unsigned short)hf[2]) * alo.z);
                    o[3] = (short)f2bf(bf2f((unsigned short)hf[3]) * alo.w);
                    o[4] = (short)f2bf(bf2f((unsigned short)hf[4]) * ahi.x);
                    o[5] = (short)f2bf(bf2f((unsigned short)hf[5]) * ahi.y);
                    o[6] = (short)f2bf(bf2f((unsigned short)hf[6]) * ahi.z);
                    o[7] = (short)f2bf(bf2f((unsigned short)hf[7]) * ahi.w);
                    af_all[rr][ks] = o;
                }
            }
        }

        for (int n = wave; n < 5; n += 4) {
            s16x8 bfr[4];
            int jr = n * 16 + l15;
            int jrc = jr < 72 ? jr : 71;
            #pragma unroll
            for (int ks = 0; ks < 4; ++ks)
                bfr[ks] = ((s16x8*)P->hl)[jrc * 16 + ((ks * 4 + l4) ^ (jrc & 7))];

            f32x4 ac0 = {0.f,0.f,0.f,0.f}, ac1 = {0.f,0.f,0.f,0.f};
            f32x4 ac2 = {0.f,0.f,0.f,0.f}, ac3 = {0.f,0.f,0.f,0.f};
            #pragma unroll
            for (int ks = 0; ks < 4; ++ks) {
                ac0 = __builtin_amdgcn_mfma_f32_16x16x32_bf16(af_all[0][ks], bfr[ks], ac0, 0, 0, 0);
                ac1 = __builtin_amdgcn_mfma_f32_16x16x32_bf16(af_all[1][ks], bfr[ks], ac1, 0, 0, 0);
                ac2 = __builtin_amdgcn_mfma_f32_16x16x32_bf16(af_all[2][ks], bfr[ks], ac2, 0, 0, 0);
                ac3 = __builtin_amdgcn_mfma_f32_16x16x32_bf16(af_all[3][ks], bfr[ks], ac3, 0, 0, 0);
            }

            #pragma unroll
            for (int reg = 0; reg < 4; ++reg) {
                int il = l4 * 4 + reg;
                int i  = i0 + il;
                int j  = n * 16 + l15;
                float v;
                if (j < S_) {
                    int ic = i < S_ ? i : S_ - 1;
                    int a  = adj[((long)b * S_ + ic) * S_ + j];
                    float raw = (a == 1) ? ac0[reg] : (a == 2) ? ac1[reg]
                              : (a == 3) ? ac2[reg] : (a == 4) ? ac3[reg] : 0.f;
                    v = (a >= 1 && a <= 4) ? (raw > 0.f ? raw : 0.2f * raw) : -9e15f;
                } else {
                    v = -INFINITY;
                }
                P->El[il * 84 + j] = v;
            }
        }
        __syncthreads();

        // phase D: row softmax + pack alpha bf16 (zero for j >= 70)
        {
            int g = tid >> 4, li = tid & 15;
            float mx = -INFINITY;
            for (int j = li; j < S_; j += 16) mx = fmaxf(mx, P->El[g * 84 + j]);
            #pragma unroll
            for (int o = 1; o < 16; o <<= 1) mx = fmaxf(mx, __shfl_xor(mx, o));
            float sm = 0.f;
            for (int j = li; j < S_; j += 16) {
                float ex = __expf(P->El[g * 84 + j] - mx);
                P->El[g * 84 + j] = ex;
                sm += ex;
            }
            #pragma unroll
            for (int o = 1; o < 16; o <<= 1) sm += __shfl_xor(sm, o);
            float inv = 1.f / sm;
            for (int j = li; j < 104; j += 16)
                P->al[g * 104 + j] = (j < S_) ? f2bf(P->El[g * 84 + j] * inv) : (unsigned short)0;
        }
        __syncthreads();

        // phase E: h_local = alpha @ H; B-frags assembled from hl columns
        for (int n = wave; n < 8; n += 4) {
            f32x4 acc = {0.f, 0.f, 0.f, 0.f};
            int d = n * 16 + l15;
            int dchunk = d >> 3, de = d & 7;
            #pragma unroll
            for (int ks = 0; ks < 3; ++ks) {
                s16x8 afp = *(const s16x8*)(P->al + l15 * 104 + ks * 32 + l4 * 8);
                int jb = ks * 32 + l4 * 8;
                s16x8 bfp;
                #pragma unroll
                for (int e = 0; e < 8; ++e) {
                    int j = jb + e;
                    bfp[e] = (j < 72)
                        ? (short)P->hl[j * 128 + ((dchunk ^ (j & 7)) << 3) + de]
                        : (short)0;
                }
                acc = __builtin_amdgcn_mfma_f32_16x16x32_bf16(afp, bfp, acc, 0, 0, 0);
            }
            #pragma unroll
            for (int reg = 0; reg < 4; ++reg) {
                int il = l4 * 4 + reg;
                if (il < IBLK)
                    out[((long)b * S_ + (i0 + il)) * D_ + d] = acc[reg];
            }
        }
    } else {
        // ================= GLOBAL role: 10 positions of h_global =================
        GlobalSM* P = &smem.glob;
        const int i0  = (r - 5) * NPOS;
        const int bs0 = b * S_ + i0;

        // phase A: neighbor ids + weights, zero pad rows 120..127
        if (tid < NR2) {
            int p = tid / NSAMP;
            int k = tid - p * NSAMP;
            int node = inputs[bs0 + p];
            P->neigh[tid] = adj_all[node * NSAMP + k];
            P->nw[tid]    = num_w[node * NSAMP + k];
        }
        if (tid < 128) ((s16x8*)P->nv)[NR2 * 16 + tid] = zero8;
        __syncthreads();

        // phase B: stage nv from bf16 table, swizzled (no cvt)
        #pragma unroll
        for (int it = 0; it < 8; ++it) {
            int idx = it * 256 + tid;
            if (idx < NR2 * 16) {
                int row = idx >> 4, c8 = idx & 15;
                s16x8 p = *(const s16x8*)(embT + (long)P->neigh[row] * D_ + c8 * 8);
                ((s16x8*)P->nv)[row * 16 + (c8 ^ (row & 7))] = p;
            }
        }
        __syncthreads();

        // phase C: B-fragments with sess folded
        s16x8 bfp[2][4];
        #pragma unroll
        for (int n = 0; n < 2; ++n) {
            int c = (wave * 2 + n) * 16 + l15;
            #pragma unroll
            for (int ks = 0; ks < 4; ++ks) {
                s16x8 g = *(const s16x8*)(gw1T + c * 128 + ks * 32 + l4 * 8);
                float4 slo = *(const float4*)(sess + b * D_ + ks * 32 + l4 * 8);
                float4 shi = *(const float4*)(sess + b * D_ + ks * 32 + l4 * 8 + 4);
                s16x8 o;
                o[0] = (short)f2bf(bf2f((unsigned short)g[0]) * slo.x);
                o[1] = (short)f2bf(bf2f((unsigned short)g[1]) * slo.y);
                o[2] = (short)f2bf(bf2f((unsigned short)g[2]) * slo.z);
                o[3] = (short)f2bf(bf2f((unsigned short)g[3]) * slo.w);
                o[4] = (short)f2bf(bf2f((unsigned short)g[4]) * shi.x);
                o[5] = (short)f2bf(bf2f((unsigned short)g[5]) * shi.y);
                o[6] = (short)f2bf(bf2f((unsigned short)g[6]) * shi.z);
                o[7] = (short)f2bf(bf2f((unsigned short)g[7]) * shi.w);
                bfp[n][ks] = o;
            }
        }
        float g128a = gw1[128 * 128 + wave * 32 + l15];
        float g128b = gw1[128 * 128 + wave * 32 + 16 + l15];
        float gw2a  = gw2[wave * 32 + l15];
        float gw2b  = gw2[wave * 32 + 16 + l15];

        // phase D: gw1 matmul over 8 M-tiles + score epilogue
        for (int m = 0; m < NRP / 16; ++m) {
            int arow = m * 16 + l15;
            s16x8 af[4];
            #pragma unroll
            for (int ks = 0; ks < 4; ++ks)
                af[ks] = ((s16x8*)P->nv)[arow * 16 + ((ks * 4 + l4) ^ (arow & 7))];

            f32x4 acc0 = {0.f, 0.f, 0.f, 0.f}, acc1 = {0.f, 0.f, 0.f, 0.f};
            #pragma unroll
            for (int ks = 0; ks < 4; ++ks) {
                acc0 = __builtin_amdgcn_mfma_f32_16x16x32_bf16(af[ks], bfp[0][ks], acc0, 0, 0, 0);
                acc1 = __builtin_amdgcn_mfma_f32_16x16x32_bf16(af[ks], bfp[1][ks], acc1, 0, 0, 0);
            }

            float sp[4];
            #pragma unroll
            for (int reg = 0; reg < 4; ++reg) {
                int rr = m * 16 + l4 * 4 + reg;
                float nwv = (rr < NR2) ? P->nw[rr] : 0.f;
                float al0 = acc0[reg] + nwv * g128a;
                float al1 = acc1[reg] + nwv * g128b;
                al0 = al0 > 0.f ? al0 : 0.2f * al0;
                al1 = al1 > 0.f ? al1 : 0.2f * al1;
                sp[reg] = al0 * gw2a + al1 * gw2b;
            }
            #pragma unroll
            for (int off = 1; off < 16; off <<= 1) {
                #pragma unroll
                for (int reg = 0; reg < 4; ++reg) sp[reg] += __shfl_xor(sp[reg], off);
            }
            if (l15 == 0) {
                int rb = m * 16 + l4 * 4;
                #pragma unroll
                for (int reg = 0; reg < 4; ++reg) P->spart[rb + reg][wave] = sp[reg];
            }
        }
        __syncthreads();

        if (tid < NR2)
            P->score[tid] = P->spart[tid][0] + P->spart[tid][1] + P->spart[tid][2] + P->spart[tid][3];
        __syncthreads();

        if (tid < NPOS) {
            float mx = -1e30f;
            #pragma unroll
            for (int k = 0; k < NSAMP; ++k) mx = fmaxf(mx, P->score[tid * NSAMP + k]);
            float ex[NSAMP]; float ss = 0.f;
            #pragma unroll
            for (int k = 0; k < NSAMP; ++k) { ex[k] = __expf(P->score[tid * NSAMP + k] - mx); ss += ex[k]; }
            float inv = 1.f / ss;
            #pragma unroll
            for (int k = 0; k < NSAMP; ++k) P->wsm[tid * NSAMP + k] = ex[k] * inv;
        }
        __syncthreads();

        // phase E: nagg from LDS nv + cat staging (h read from bf16 table)
        {
            int p  = tid >> 4;
            int c8 = tid & 15;
            if (p < NPOS) {
                float a0v[4] = {0.f,0.f,0.f,0.f}, a1v[4] = {0.f,0.f,0.f,0.f};
                #pragma unroll
                for (int k = 0; k < NSAMP; ++k) {
                    int row = p * NSAMP + k;
                    float w = P->wsm[row];
                    s16x8 nvv = ((s16x8*)P->nv)[row * 16 + (c8 ^ (row & 7))];
                    a0v[0] += w * bf2f((unsigned short)nvv[0]);
                    a0v[1] += w * bf2f((unsigned short)nvv[1]);
                    a0v[2] += w * bf2f((unsigned short)nvv[2]);
                    a0v[3] += w * bf2f((unsigned short)nvv[3]);
                    a1v[0] += w * bf2f((unsigned short)nvv[4]);
                    a1v[1] += w * bf2f((unsigned short)nvv[5]);
                    a1v[2] += w * bf2f((unsigned short)nvv[6]);
                    a1v[3] += w * bf2f((unsigned short)nvv[7]);
                }
                int node = inputs[bs0 + p];
                s16x8 ph = *(const s16x8*)(embT + (long)node * D_ + c8 * 8);
                s16x8 pa;
                pa[0]=(short)f2bf(a0v[0]); pa[1]=(short)f2bf(a0v[1]); pa[2]=(short)f2bf(a0v[2]); pa[3]=(short)f2bf(a0v[3]);
                pa[4]=(short)f2bf(a1v[0]); pa[5]=(short)f2bf(a1v[1]); pa[6]=(short)f2bf(a1v[2]); pa[7]=(short)f2bf(a1v[3]);
                ((s16x8*)P->cat)[p * 32 + ( c8       ^ (p & 7))] = ph;
                ((s16x8*)P->cat)[p * 32 + ((16 + c8) ^ (p & 7))] = pa;
            } else {
                ((s16x8*)P->cat)[p * 32 + ( c8       ^ (p & 7))] = zero8;
                ((s16x8*)P->cat)[p * 32 + ((16 + c8) ^ (p & 7))] = zero8;
            }
        }
        __syncthreads();

        // phase F: gw3 matmul + bias + relu
        {
            f32x4 acc0 = {0.f,0.f,0.f,0.f}, acc1 = {0.f,0.f,0.f,0.f};
            int arow = l15;
            int cc = wave * 32 + l15;
            #pragma unroll
            for (int ks = 0; ks < 8; ++ks) {
                s16x8 a  = ((s16x8*)P->cat)[arow * 32 + ((ks * 4 + l4) ^ (arow & 7))];
                s16x8 b0 = *(const s16x8*)(gw3T +  cc       * 256 + ks * 32 + l4 * 8);
                s16x8 b1 = *(const s16x8*)(gw3T + (cc + 16) * 256 + ks * 32 + l4 * 8);
                acc0 = __builtin_amdgcn_mfma_f32_16x16x32_bf16(a, b0, acc0, 0, 0, 0);
                acc1 = __builtin_amdgcn_mfma_f32_16x16x32_bf16(a, b1, acc1, 0, 0, 0);
            }
            float gb0 = gbias[wave * 32 + l15];
            float gb1 = gbias[wave * 32 + 16 + l15];
            #pragma unroll
            for (int reg = 0; reg < 4; ++reg) {
                int il = l4 * 4 + reg;
                if (il < NPOS) {
                    long bs = bs0 + il;
                    float o0 = acc0[reg] + gb0;
                    float o1 = acc1[reg] + gb1;
                    out[(long)HGLOB + bs * D_ + wave * 32 + l15]      = o0 > 0.f ? o0 : 0.f;
                    out[(long)HGLOB + bs * D_ + wave * 32 + 16 + l15] = o1 > 0.f ? o1 : 0.f;
                }
            }
        }
    }
}

extern "C" void kernel_launch(void* const* d_in, const int* in_sizes, int n_in,
                              void* d_out, int out_size, void* d_ws, size_t ws_size,
                              hipStream_t stream) {
    const int*   inputs  = (const int*)  d_in[0];
    const int*   adj     = (const int*)  d_in[1];
    const int*   mask    = (const int*)  d_in[2];
    const int*   item    = (const int*)  d_in[3];
    const int*   adj_all = (const int*)  d_in[5];
    const float* num_w   = (const float*)d_in[6];
    const float* emb     = (const float*)d_in[7];
    const float* a0      = (const float*)d_in[8];
    const float* a1      = (const float*)d_in[9];
    const float* a2      = (const float*)d_in[10];
    const float* a3      = (const float*)d_in[11];
    const float* gw1     = (const float*)d_in[12];
    const float* gw2     = (const float*)d_in[13];
    const float* gw3     = (const float*)d_in[14];
    const float* gbias   = (const float*)d_in[15];
    float* out = (float*)d_out;

    float*          sess = (float*)d_ws;                              // 131072 B
    unsigned short* gw1T = (unsigned short*)((char*)d_ws + 131072);   // 32768 B
    unsigned short* gw3T = gw1T + 128 * 128;                          // 65536 B
    unsigned short* embT = gw3T + 128 * 256;                          // 10,240,000 B

    const int embt_blocks = (NNODE * D_ / 8 + 511) / 512;             // 1250
    prelude_kernel<<<B_ + 96 + embt_blocks, 512, 0, stream>>>(item, mask, emb, gw1, gw3,
                                                              sess, gw1T, gw3T, embT);
    fused_kernel<<<B_ * 12, 256, 0, stream>>>(inputs, adj, adj_all, num_w, embT, sess,
                                              a0, a1, a2, a3,
                                              gw1T, gw1, gw2, gw3T, gbias, out);
}